// Round 3
// baseline (428.243 us; speedup 1.0000x reference)
//
#include <hip/hip_runtime.h>
#include <stdint.h>

// ---------------------------------------------------------------------------
// StageBranchRunnerN2 round 2:
//  - expert path made top-2 SPARSE: gate -> per-expert token lists (atomic
//    counts, prefix, tile map) -> grouped GEMM1 (gathered A rows, K=1024)
//    -> grouped GEMM2 (compact pair rows, K=256) -> combine (pairA+pairB+
//    gated e_b2, + residual).  68.7 GF dense -> 17.2 GF sparse.
//  - proj2 folded into router GEMM: W' = fp_w2 @ r_w1[1024:], b' = r_b1 +
//    fp_b2 @ r_w1[1024:].  Removes one gemm3 + epilogue.
//  - router/proj remain split-bf16 3-product MFMA (top-2 tie safety).
// ---------------------------------------------------------------------------

typedef unsigned short u16;
using bf16x8 = __attribute__((ext_vector_type(8))) short;
using f32x4  = __attribute__((ext_vector_type(4))) float;

// ws layout (proven ws >= 75,497,472 B; we use < 68.1 MB)
#define WS_HHI 0u
#define WS_HLO 16777216u
#define WS_PB2 33554432u
#define WS_IDX 67108864u
// idx sub-offsets (bytes from ws+WS_IDX)
#define IX_TOK    0u        // int[8*8192]
#define IX_GPOS   262144u   // float[8*8192]
#define IX_SELE   524288u   // int[8192*2]
#define IX_SELP   589824u   // int[8192*2]
#define IX_SELG   655360u   // float[8192*2]
#define IX_ROW    720896u   // int[8192*2]
#define IX_TILEE  786432u   // int[160]
#define IX_TILEL  790528u   // int[160]
#define IX_TILES  794624u   // int[160]
#define IX_TILEC  798720u   // int[160]
#define IX_META   802816u   // int[32]: [0..7]=cnt, [16]=nTiles

__device__ __forceinline__ float gelu_tanh(float x) {
  float x3 = x * x * x;
  float t = tanhf(0.7978845608028654f * (x + 0.044715f * x3));
  return 0.5f * x * (1.0f + t);
}
__device__ __forceinline__ u16 f2bf(float f) {
  uint32_t u = __float_as_uint(f);
  u = u + 0x7fffu + ((u >> 16) & 1u);
  return (u16)(u >> 16);
}
__device__ __forceinline__ float b2f(u16 h) {
  return __uint_as_float(((uint32_t)h) << 16);
}
__device__ __forceinline__ void gll16(const void* g, void* l) {
  __builtin_amdgcn_global_load_lds(
      (const __attribute__((address_space(1))) void*)g,
      (__attribute__((address_space(3))) void*)l, 16, 0, 0);
}

// ---------------------------------------------------------------------------
__global__ __launch_bounds__(256) void split_bank_kernel(const float* __restrict__ x,
    u16* __restrict__ hi, u16* __restrict__ lo) {
  int i4 = blockIdx.x * 256 + threadIdx.x;
  float4 v = ((const float4*)x)[i4];
  ushort4 h, l;
  h.x = f2bf(v.x); l.x = f2bf(v.x - b2f(h.x));
  h.y = f2bf(v.y); l.y = f2bf(v.y - b2f(h.y));
  h.z = f2bf(v.z); l.z = f2bf(v.z - b2f(h.z));
  h.w = f2bf(v.w); l.w = f2bf(v.w - b2f(h.w));
  ((ushort4*)hi)[i4] = h;
  ((ushort4*)lo)[i4] = l;
}

// ---------------------------------------------------------------------------
// W' = fp_w2 @ r_w1[1024:1280,:]  (f32 exact-ish), block 256 = b' row.
// ---------------------------------------------------------------------------
__global__ __launch_bounds__(256) void wprime_kernel(const float* __restrict__ fp_w2,
    const float* __restrict__ r_w1, const float* __restrict__ fp_b2,
    const float* __restrict__ r_b1, float* __restrict__ wp, float* __restrict__ bp) {
  __shared__ float row[256];
  int i = blockIdx.x, n = threadIdx.x;
  if (i < 256) {
    row[n] = fp_w2[i * 256 + n];
    __syncthreads();
    float acc = 0.0f;
    for (int j = 0; j < 256; j++) acc += row[j] * r_w1[(size_t)(1024 + j) * 256 + n];
    wp[i * 256 + n] = acc;
  } else {
    row[n] = fp_b2[n];
    __syncthreads();
    float acc = r_b1[n];
    for (int j = 0; j < 256; j++) acc += row[j] * r_w1[(size_t)(1024 + j) * 256 + n];
    bp[n] = acc;
  }
}

// ---------------------------------------------------------------------------
// prep: fp_w1 -> B^T hi/lo [256][512]; e_w1 -> w1t [2048][1024] bf16;
//       e_w2 -> w2te [(e*1024+d)][256] bf16
// ---------------------------------------------------------------------------
__global__ __launch_bounds__(256) void prep_main_kernel(
    const float* __restrict__ fp_w1, const float* __restrict__ e_w1,
    const float* __restrict__ e_w2,
    u16* __restrict__ w1h, u16* __restrict__ w1l,
    u16* __restrict__ w1t, u16* __restrict__ w2te) {
  int idx = blockIdx.x * 256 + threadIdx.x;   // 131072 + 2M + 2M
  if (idx < 131072) {
    int n = idx >> 9, k = idx & 511;
    float v = fp_w1[k * 256 + n];
    u16 h = f2bf(v); w1h[idx] = h; w1l[idx] = f2bf(v - b2f(h));
  } else if (idx < 131072 + 2097152) {
    int j = idx - 131072;
    int k = j & 1023, n = j >> 10;
    int e = n >> 8, h = n & 255;
    w1t[j] = f2bf(e_w1[(e << 18) + (k << 8) + h]);
  } else {
    int j = idx - 131072 - 2097152;
    int h = j & 255, row = j >> 8;
    int d = row & 1023, e = row >> 10;
    w2te[j] = f2bf(e_w2[(e << 18) + (h << 10) + d]);
  }
}

// rw1t hi/lo [256][1280]: k<1024 from r_w1, else from W'
__global__ __launch_bounds__(256) void prep_rw_kernel(const float* __restrict__ r_w1,
    const float* __restrict__ wp, u16* __restrict__ rh, u16* __restrict__ rl) {
  int idx = blockIdx.x * 256 + threadIdx.x;   // 327680
  int n = idx / 1280, k = idx - n * 1280;
  float v = (k < 1024) ? r_w1[(size_t)k * 256 + n] : wp[(k - 1024) * 256 + n];
  u16 h = f2bf(v); rh[idx] = h; rl[idx] = f2bf(v - b2f(h));
}

// ---------------------------------------------------------------------------
// LayerNorm -> h hi/lo bf16 split; rule logits.
// ---------------------------------------------------------------------------
__global__ __launch_bounds__(256) void ln_kernel(const float* __restrict__ hidden,
    const float* __restrict__ ln_g, const float* __restrict__ ln_b,
    const float* __restrict__ feat, const float* __restrict__ rr_w,
    const float* __restrict__ rr_b,
    u16* __restrict__ h_hi, u16* __restrict__ h_lo, float* __restrict__ rule) {
  int t = blockIdx.x;
  int tid = threadIdx.x;
  float4 v = ((const float4*)(hidden + (size_t)t * 1024))[tid];
  float s = v.x + v.y + v.z + v.w;
#pragma unroll
  for (int o = 32; o > 0; o >>= 1) s += __shfl_down(s, o);
  __shared__ float red[4];
  __shared__ float stats[2];
  int wid = tid >> 6, lane = tid & 63;
  if (lane == 0) red[wid] = s;
  __syncthreads();
  if (tid == 0) stats[0] = (red[0] + red[1] + red[2] + red[3]) * (1.0f / 1024.0f);
  __syncthreads();
  float mu = stats[0];
  float dx = v.x - mu, dy = v.y - mu, dz = v.z - mu, dw = v.w - mu;
  float q = dx * dx + dy * dy + dz * dz + dw * dw;
#pragma unroll
  for (int o = 32; o > 0; o >>= 1) q += __shfl_down(q, o);
  if (lane == 0) red[wid] = q;
  __syncthreads();
  if (tid == 0) {
    float var = (red[0] + red[1] + red[2] + red[3]) * (1.0f / 1024.0f) + 1e-5f;
    float r = rsqrtf(var);
    r = r * (1.5f - 0.5f * var * r * r);
    stats[1] = r;
  }
  __syncthreads();
  float r = stats[1];
  float4 g = ((const float4*)ln_g)[tid];
  float4 b = ((const float4*)ln_b)[tid];
  float4 o;
  o.x = dx * r * g.x + b.x;
  o.y = dy * r * g.y + b.y;
  o.z = dz * r * g.z + b.z;
  o.w = dw * r * g.w + b.w;
  ushort4 hv, lv;
  hv.x = f2bf(o.x); lv.x = f2bf(o.x - b2f(hv.x));
  hv.y = f2bf(o.y); lv.y = f2bf(o.y - b2f(hv.y));
  hv.z = f2bf(o.z); lv.z = f2bf(o.z - b2f(hv.z));
  hv.w = f2bf(o.w); lv.w = f2bf(o.w - b2f(hv.w));
  ((ushort4*)(h_hi + (size_t)t * 1024))[tid] = hv;
  ((ushort4*)(h_lo + (size_t)t * 1024))[tid] = lv;
  if (tid < 8) {
    float acc = rr_b[tid];
#pragma unroll
    for (int f = 0; f < 16; f++) acc += feat[t * 16 + f] * rr_w[f * 8 + tid];
    rule[t * 8 + tid] = acc;
  }
}

// ---------------------------------------------------------------------------
// split-bf16 3-product MFMA GEMM with split-K (see round 1).
// ---------------------------------------------------------------------------
__global__ __launch_bounds__(256) void gemm3_kernel(
    const u16* __restrict__ Ah, const u16* __restrict__ Al, int lda,
    int kchunk, int nz1,
    const u16* __restrict__ A2h, const u16* __restrict__ A2l, int lda2,
    int klen2, int bkoff2,
    const u16* __restrict__ Bth, const u16* __restrict__ Btl, int Kb,
    float* __restrict__ parts) {
  __shared__ u16 Ash[128 * 32];
  __shared__ u16 Asl[128 * 32];
  __shared__ u16 Bsh[128 * 32];
  __shared__ u16 Bsl[128 * 32];
  int tid = threadIdx.x;
  int z = blockIdx.z;
  const u16 *pAh, *pAl;
  int lda_, akoff, bkoff, klen;
  if (z < nz1) {
    pAh = Ah; pAl = Al; lda_ = lda; akoff = z * kchunk; bkoff = akoff; klen = kchunk;
  } else {
    pAh = A2h; pAl = A2l; lda_ = lda2; akoff = 0; bkoff = bkoff2; klen = klen2;
  }
  int row0 = blockIdx.y * 128, col0 = blockIdx.x * 128;
  int wave = tid >> 6, lane = tid & 63;
  int wr = (wave >> 1) * 64, wc = (wave & 1) * 64;
  int l16 = lane & 15, qd = lane >> 4;
  f32x4 acc[4][4];
#pragma unroll
  for (int i = 0; i < 4; i++)
#pragma unroll
    for (int j = 0; j < 4; j++) acc[i][j] = 0.0f;

  int r0 = tid >> 2, kc = tid & 3;
  const u16* gAh0 = pAh + (size_t)(row0 + r0) * lda_ + akoff + kc * 8;
  const u16* gAh1 = gAh0 + (size_t)64 * lda_;
  const u16* gAl0 = pAl + (size_t)(row0 + r0) * lda_ + akoff + kc * 8;
  const u16* gAl1 = gAl0 + (size_t)64 * lda_;
  const u16* gBh0 = Bth + (size_t)(col0 + r0) * Kb + bkoff + kc * 8;
  const u16* gBh1 = gBh0 + (size_t)64 * Kb;
  const u16* gBl0 = Btl + (size_t)(col0 + r0) * Kb + bkoff + kc * 8;
  const u16* gBl1 = gBl0 + (size_t)64 * Kb;
  u16* dAh = Ash + tid * 8;
  u16* dAl = Asl + tid * 8;
  u16* dBh = Bsh + tid * 8;
  u16* dBl = Bsl + tid * 8;

  for (int k0 = 0; k0 < klen; k0 += 32) {
    __syncthreads();
    gll16(gAh0 + k0, dAh);
    gll16(gAh1 + k0, dAh + 2048);
    gll16(gAl0 + k0, dAl);
    gll16(gAl1 + k0, dAl + 2048);
    gll16(gBh0 + k0, dBh);
    gll16(gBh1 + k0, dBh + 2048);
    gll16(gBl0 + k0, dBl);
    gll16(gBl1 + k0, dBl + 2048);
    __syncthreads();
    bf16x8 afh[4], afl[4], bfh[4], bfl[4];
#pragma unroll
    for (int i = 0; i < 4; i++) {
      afh[i] = *((const bf16x8*)(Ash + (wr + i * 16 + l16) * 32 + qd * 8));
      afl[i] = *((const bf16x8*)(Asl + (wr + i * 16 + l16) * 32 + qd * 8));
      bfh[i] = *((const bf16x8*)(Bsh + (wc + i * 16 + l16) * 32 + qd * 8));
      bfl[i] = *((const bf16x8*)(Bsl + (wc + i * 16 + l16) * 32 + qd * 8));
    }
#pragma unroll
    for (int i = 0; i < 4; i++)
#pragma unroll
      for (int j = 0; j < 4; j++) {
        acc[i][j] = __builtin_amdgcn_mfma_f32_16x16x32_bf16(afh[i], bfh[j], acc[i][j], 0, 0, 0);
        acc[i][j] = __builtin_amdgcn_mfma_f32_16x16x32_bf16(afl[i], bfh[j], acc[i][j], 0, 0, 0);
        acc[i][j] = __builtin_amdgcn_mfma_f32_16x16x32_bf16(afh[i], bfl[j], acc[i][j], 0, 0, 0);
      }
  }

  float* pz = parts + (size_t)z * 2097152;
#pragma unroll
  for (int i = 0; i < 4; i++)
#pragma unroll
    for (int j = 0; j < 4; j++) {
      int cl = wc + j * 16 + l16;
#pragma unroll
      for (int rr = 0; rr < 4; rr++) {
        int rl = wr + i * 16 + qd * 4 + rr;
        pz[(size_t)(row0 + rl) * 256 + col0 + cl] = acc[i][j][rr];
      }
    }
}

// ---------------------------------------------------------------------------
__global__ __launch_bounds__(256) void epi_bf_kernel(const float* __restrict__ parts,
    int nz, const float* __restrict__ bias, int do_gelu,
    u16* __restrict__ hi, u16* __restrict__ lo) {
  int i4 = blockIdx.x * 256 + threadIdx.x;
  float4 s = ((const float4*)parts)[i4];
  for (int zz = 1; zz < nz; zz++) {
    float4 p = ((const float4*)parts)[(size_t)zz * 524288 + i4];
    s.x += p.x; s.y += p.y; s.z += p.z; s.w += p.w;
  }
  float4 bv = ((const float4*)bias)[i4 & 63];
  s.x += bv.x; s.y += bv.y; s.z += bv.z; s.w += bv.w;
  if (do_gelu) {
    s.x = gelu_tanh(s.x); s.y = gelu_tanh(s.y);
    s.z = gelu_tanh(s.z); s.w = gelu_tanh(s.w);
  }
  ushort4 h, l;
  h.x = f2bf(s.x); l.x = f2bf(s.x - b2f(h.x));
  h.y = f2bf(s.y); l.y = f2bf(s.y - b2f(h.y));
  h.z = f2bf(s.z); l.z = f2bf(s.z - b2f(h.z));
  h.w = f2bf(s.w); l.w = f2bf(s.w - b2f(h.w));
  ((ushort4*)hi)[i4] = h;
  ((ushort4*)lo)[i4] = l;
}

__global__ __launch_bounds__(256) void epi_f32_kernel(const float* __restrict__ parts,
    int nz, const float* __restrict__ bias, float* __restrict__ out) {
  int i4 = blockIdx.x * 256 + threadIdx.x;
  float4 s = ((const float4*)parts)[i4];
  for (int zz = 1; zz < nz; zz++) {
    float4 p = ((const float4*)parts)[(size_t)zz * 524288 + i4];
    s.x += p.x; s.y += p.y; s.z += p.z; s.w += p.w;
  }
  float4 bv = ((const float4*)bias)[i4 & 63];
  s.x = gelu_tanh(s.x + bv.x);
  s.y = gelu_tanh(s.y + bv.y);
  s.z = gelu_tanh(s.z + bv.z);
  s.w = gelu_tanh(s.w + bv.w);
  ((float4*)out)[i4] = s;
}

// ---------------------------------------------------------------------------
// Router head + top-2 select + per-expert index build.
// ---------------------------------------------------------------------------
__global__ __launch_bounds__(256) void gate_kernel(const float* __restrict__ r1,
    const float* __restrict__ r_w2, const float* __restrict__ r_b2,
    float* __restrict__ gates, float* __restrict__ slog, float* __restrict__ gw,
    int* __restrict__ tok, float* __restrict__ gpos,
    int* __restrict__ selE, int* __restrict__ selP, float* __restrict__ selG,
    int* __restrict__ meta) {
  __shared__ float w2s[2048];
  __shared__ float r1s[32][260];
  __shared__ float lg[32][8];
  int tid = threadIdx.x;
  int t0 = blockIdx.x * 32;
  for (int i = tid; i < 2048; i += 256) w2s[i] = r_w2[i];
  for (int i = tid; i < 32 * 256; i += 256) {
    int tt = i >> 8, k = i & 255;
    r1s[tt][k] = r1[(size_t)(t0 + tt) * 256 + k];
  }
  __syncthreads();
  int tl = tid >> 3, e = tid & 7;
  float acc = r_b2[e];
  for (int k = 0; k < 256; k++) acc += r1s[tl][k] * w2s[k * 8 + e];
  lg[tl][e] = acc;
  __syncthreads();
  if (tid < 32) {
    int t = t0 + tid;
    float l[8];
#pragma unroll
    for (int i = 0; i < 8; i++) l[i] = lg[tid][i];
    float m1 = -1e30f, m2 = -1e30f;
    int i1 = 0, i2 = 0;
#pragma unroll
    for (int i = 0; i < 8; i++) {
      float v = l[i];
      if (v > m1) { m2 = m1; i2 = i1; m1 = v; i1 = i; }
      else if (v > m2) { m2 = v; i2 = i; }
    }
    float w[8];
    float se = 0.0f;
#pragma unroll
    for (int i = 0; i < 8; i++) {
      float ex = (l[i] >= m2) ? expf(l[i] - m1) : 0.0f;
      w[i] = ex;
      se += ex;
    }
    float inv = 1.0f / se;
#pragma unroll
    for (int i = 0; i < 8; i++) {
      gates[(size_t)t * 8 + i] = w[i] * inv;
      slog[(size_t)t * 8 + i] = l[i];
    }
#pragma unroll
    for (int gi = 0; gi < 4; gi++)
      gw[(size_t)t * 4 + gi] = (w[2 * gi] + w[2 * gi + 1]) * inv;
    // sparse index build
    float g1 = w[i1] * inv, g2 = w[i2] * inv;
    int p1 = atomicAdd(&meta[i1], 1);
    tok[i1 * 8192 + p1] = t; gpos[i1 * 8192 + p1] = g1;
    selE[t * 2] = i1; selP[t * 2] = p1; selG[t * 2] = g1;
    int p2 = atomicAdd(&meta[i2], 1);
    tok[i2 * 8192 + p2] = t; gpos[i2 * 8192 + p2] = g2;
    selE[t * 2 + 1] = i2; selP[t * 2 + 1] = p2; selG[t * 2 + 1] = g2;
  }
}

// ---------------------------------------------------------------------------
// tile map: base prefix, tiles, rowsel.
// ---------------------------------------------------------------------------
__global__ __launch_bounds__(256) void tilemap_kernel(int* __restrict__ meta,
    int* __restrict__ tileE, int* __restrict__ tileL, int* __restrict__ tileS,
    int* __restrict__ tileC, const int* __restrict__ selE,
    const int* __restrict__ selP, int* __restrict__ rowsel) {
  __shared__ int sbase[8];
  int tid = threadIdx.x;
  if (tid == 0) {
    int b = 0, nt = 0;
    for (int e = 0; e < 8; e++) {
      sbase[e] = b;
      int c = meta[e];
      for (int off = 0; off < c; off += 128) {
        tileE[nt] = e; tileL[nt] = off; tileS[nt] = b + off;
        tileC[nt] = (c - off < 128) ? (c - off) : 128;
        nt++;
      }
      b += c;
    }
    meta[16] = nt;
  }
  __syncthreads();
  for (int i = tid; i < 16384; i += 256)
    rowsel[i] = sbase[selE[i]] + selP[i];
}

// ---------------------------------------------------------------------------
// sparse grouped GEMM1: pairs x 256 = gelu(gather(h_hi) @ w1t_e + b1_e) * g
// grid (2, 136). K=1024.
// ---------------------------------------------------------------------------
__global__ __launch_bounds__(256) void gexp1_kernel(const u16* __restrict__ A,
    const u16* __restrict__ w1t, const float* __restrict__ e_b1,
    const int* __restrict__ tok, const float* __restrict__ gpos,
    const int* __restrict__ tileE, const int* __restrict__ tileL,
    const int* __restrict__ tileS, const int* __restrict__ tileC,
    const int* __restrict__ meta, u16* __restrict__ pb1) {
  int ty = blockIdx.y;
  if (ty >= meta[16]) return;
  int e = tileE[ty], loc = tileL[ty], pstart = tileS[ty], pcnt = tileC[ty];
  if (pcnt <= 0) return;
  __shared__ u16 As[128 * 32];
  __shared__ u16 Bs[128 * 32];
  __shared__ float gsl[128];
  int tid = threadIdx.x;
  int col0 = blockIdx.x * 128;
  if (tid < 128) {
    int rr = (tid < pcnt) ? tid : (pcnt - 1);
    gsl[tid] = gpos[e * 8192 + loc + rr];
  }
  int wave = tid >> 6, lane = tid & 63;
  int wr = (wave >> 1) * 64, wc = (wave & 1) * 64;
  int l16 = lane & 15, qd = lane >> 4;
  f32x4 acc[4][4];
#pragma unroll
  for (int i = 0; i < 4; i++)
#pragma unroll
    for (int j = 0; j < 4; j++) acc[i][j] = 0.0f;

  int r0 = tid >> 2, kc = tid & 3;
  int ra = (r0 < pcnt) ? r0 : (pcnt - 1);
  int rb = (r0 + 64 < pcnt) ? (r0 + 64) : (pcnt - 1);
  int ta = tok[e * 8192 + loc + ra];
  int tb = tok[e * 8192 + loc + rb];
  const u16* Ap0 = A + (size_t)ta * 1024 + kc * 8;
  const u16* Ap1 = A + (size_t)tb * 1024 + kc * 8;
  const u16* Bp0 = w1t + (size_t)(e * 256 + col0 + r0) * 1024 + kc * 8;
  const u16* Bp1 = Bp0 + (size_t)64 * 1024;
  u16* dA = As + tid * 8;
  u16* dB = Bs + tid * 8;

  for (int k0 = 0; k0 < 1024; k0 += 32) {
    __syncthreads();
    gll16(Ap0 + k0, dA);
    gll16(Ap1 + k0, dA + 2048);
    gll16(Bp0 + k0, dB);
    gll16(Bp1 + k0, dB + 2048);
    __syncthreads();
    bf16x8 af[4], bfr[4];
#pragma unroll
    for (int i = 0; i < 4; i++) {
      af[i]  = *((const bf16x8*)(As + (wr + i * 16 + l16) * 32 + qd * 8));
      bfr[i] = *((const bf16x8*)(Bs + (wc + i * 16 + l16) * 32 + qd * 8));
    }
#pragma unroll
    for (int i = 0; i < 4; i++)
#pragma unroll
      for (int j = 0; j < 4; j++)
        acc[i][j] = __builtin_amdgcn_mfma_f32_16x16x32_bf16(af[i], bfr[j], acc[i][j], 0, 0, 0);
  }

#pragma unroll
  for (int i = 0; i < 4; i++)
#pragma unroll
    for (int j = 0; j < 4; j++) {
      int cl = wc + j * 16 + l16;
      int col = col0 + cl;
      float bcol = e_b1[e * 256 + col];
#pragma unroll
      for (int rr = 0; rr < 4; rr++) {
        int rl = wr + i * 16 + qd * 4 + rr;
        if (rl < pcnt) {
          float v = gelu_tanh(acc[i][j][rr] + bcol) * gsl[rl];
          pb1[(size_t)(pstart + rl) * 256 + col] = f2bf(v);
        }
      }
    }
}

// ---------------------------------------------------------------------------
// sparse grouped GEMM2: pairs x 1024 = pb1 @ w2te_e. grid (8, 136). K=256.
// ---------------------------------------------------------------------------
__global__ __launch_bounds__(256) void gexp2_kernel(const u16* __restrict__ pb1,
    const u16* __restrict__ w2te,
    const int* __restrict__ tileE, const int* __restrict__ tileS,
    const int* __restrict__ tileC, const int* __restrict__ meta,
    u16* __restrict__ pb2) {
  int ty = blockIdx.y;
  if (ty >= meta[16]) return;
  int e = tileE[ty], pstart = tileS[ty], pcnt = tileC[ty];
  if (pcnt <= 0) return;
  __shared__ u16 As[128 * 32];
  __shared__ u16 Bs[128 * 32];
  int tid = threadIdx.x;
  int col0 = blockIdx.x * 128;
  int wave = tid >> 6, lane = tid & 63;
  int wr = (wave >> 1) * 64, wc = (wave & 1) * 64;
  int l16 = lane & 15, qd = lane >> 4;
  f32x4 acc[4][4];
#pragma unroll
  for (int i = 0; i < 4; i++)
#pragma unroll
    for (int j = 0; j < 4; j++) acc[i][j] = 0.0f;

  int r0 = tid >> 2, kc = tid & 3;
  int ra = (r0 < pcnt) ? r0 : (pcnt - 1);
  int rb = (r0 + 64 < pcnt) ? (r0 + 64) : (pcnt - 1);
  const u16* Ap0 = pb1 + (size_t)(pstart + ra) * 256 + kc * 8;
  const u16* Ap1 = pb1 + (size_t)(pstart + rb) * 256 + kc * 8;
  const u16* Bp0 = w2te + (size_t)(e * 1024 + col0 + r0) * 256 + kc * 8;
  const u16* Bp1 = Bp0 + (size_t)64 * 256;
  u16* dA = As + tid * 8;
  u16* dB = Bs + tid * 8;

  for (int k0 = 0; k0 < 256; k0 += 32) {
    __syncthreads();
    gll16(Ap0 + k0, dA);
    gll16(Ap1 + k0, dA + 2048);
    gll16(Bp0 + k0, dB);
    gll16(Bp1 + k0, dB + 2048);
    __syncthreads();
    bf16x8 af[4], bfr[4];
#pragma unroll
    for (int i = 0; i < 4; i++) {
      af[i]  = *((const bf16x8*)(As + (wr + i * 16 + l16) * 32 + qd * 8));
      bfr[i] = *((const bf16x8*)(Bs + (wc + i * 16 + l16) * 32 + qd * 8));
    }
#pragma unroll
    for (int i = 0; i < 4; i++)
#pragma unroll
      for (int j = 0; j < 4; j++)
        acc[i][j] = __builtin_amdgcn_mfma_f32_16x16x32_bf16(af[i], bfr[j], acc[i][j], 0, 0, 0);
  }

#pragma unroll
  for (int i = 0; i < 4; i++)
#pragma unroll
    for (int j = 0; j < 4; j++) {
      int cl = wc + j * 16 + l16;
#pragma unroll
      for (int rr = 0; rr < 4; rr++) {
        int rl = wr + i * 16 + qd * 4 + rr;
        if (rl < pcnt)
          pb2[(size_t)(pstart + rl) * 1024 + col0 + cl] = f2bf(acc[i][j][rr]);
      }
    }
}

// ---------------------------------------------------------------------------
// combine: stage = pairA + pairB + gA*b2[eA] + gB*b2[eB]; next = hidden+a*st.
// ---------------------------------------------------------------------------
__global__ __launch_bounds__(256) void combine_kernel(const u16* __restrict__ pb2,
    const int* __restrict__ rowsel, const int* __restrict__ selE,
    const float* __restrict__ selG, const float* __restrict__ e_b2,
    const float* __restrict__ hidden, const float* __restrict__ alpha_p,
    float* __restrict__ stage, float* __restrict__ next) {
  int t = blockIdx.x;
  int c = threadIdx.x * 4;
  int rA = rowsel[t * 2], rB = rowsel[t * 2 + 1];
  int eA = selE[t * 2], eB = selE[t * 2 + 1];
  float gA = selG[t * 2], gB = selG[t * 2 + 1];
  float al = alpha_p[0];
  ushort4 pa = *((const ushort4*)(pb2 + (size_t)rA * 1024 + c));
  ushort4 pb = *((const ushort4*)(pb2 + (size_t)rB * 1024 + c));
  float4 ba = *((const float4*)(e_b2 + (size_t)eA * 1024 + c));
  float4 bb = *((const float4*)(e_b2 + (size_t)eB * 1024 + c));
  float4 h = *((const float4*)(hidden + (size_t)t * 1024 + c));
  float4 v;
  v.x = b2f(pa.x) + b2f(pb.x) + gA * ba.x + gB * bb.x;
  v.y = b2f(pa.y) + b2f(pb.y) + gA * ba.y + gB * bb.y;
  v.z = b2f(pa.z) + b2f(pb.z) + gA * ba.z + gB * bb.z;
  v.w = b2f(pa.w) + b2f(pb.w) + gA * ba.w + gB * bb.w;
  *((float4*)(stage + (size_t)t * 1024 + c)) = v;
  float4 n;
  n.x = h.x + al * v.x; n.y = h.y + al * v.y;
  n.z = h.z + al * v.z; n.w = h.w + al * v.w;
  *((float4*)(next + (size_t)t * 1024 + c)) = n;
}

// ---------------------------------------------------------------------------
extern "C" void kernel_launch(void* const* d_in, const int* in_sizes, int n_in,
                              void* d_out, int out_size, void* d_ws, size_t ws_size,
                              hipStream_t stream) {
  const float* hidden    = (const float*)d_in[0];
  const float* feat      = (const float*)d_in[1];
  const float* feat_bank = (const float*)d_in[2];
  const float* ln_g  = (const float*)d_in[4];
  const float* ln_b  = (const float*)d_in[5];
  const float* fp_w1 = (const float*)d_in[6];
  const float* fp_b1 = (const float*)d_in[7];
  const float* fp_w2 = (const float*)d_in[8];
  const float* fp_b2 = (const float*)d_in[9];
  const float* r_w1  = (const float*)d_in[10];
  const float* r_b1  = (const float*)d_in[11];
  const float* r_w2  = (const float*)d_in[12];
  const float* r_b2  = (const float*)d_in[13];
  const float* rr_w  = (const float*)d_in[14];
  const float* rr_b  = (const float*)d_in[15];
  const float* e_w1  = (const float*)d_in[16];
  const float* e_b1  = (const float*)d_in[17];
  const float* e_w2  = (const float*)d_in[18];
  const float* e_b2  = (const float*)d_in[19];
  const float* alpha = (const float*)d_in[20];

  char* ob = (char*)d_out;
  float* next  = (float*)ob;
  float* stage = (float*)(ob + 33554432);
  float* gates = (float*)(ob + 67108864);
  float* slog  = gates + 65536;
  float* gw    = slog + 65536;
  float* rule  = gw + 32768;

  // next-region scratch (all dead before combine writes next)
  u16* bank_hi  = (u16*)ob;                      // 8M  [-> proj1 gemm]
  u16* bank_lo  = (u16*)(ob + 8388608);          // 8M
  float* r1     = (float*)ob;                    // 8M  [epi_f32 -> gate; after bank dead]
  u16* fpw1t_hi = (u16*)(ob + 16777216);         // 256K [-> proj1 gemm]
  u16* fpw1t_lo = (u16*)(ob + 17039360);         // 256K
  float* wp     = (float*)(ob + 17301504);       // 256K [wprime -> prep_rw]
  float* bp     = (float*)(ob + 17563648);       // 1K   [-> epi_f32]
  u16* rw1t_hi  = (u16*)(ob + 17825792);         // 640K [-> router gemm]
  u16* rw1t_lo  = (u16*)(ob + 18481152);         // 640K
  u16* mid_hi   = (u16*)(ob + 19136512);         // 4M   [epi1 -> router gemm]
  u16* mid_lo   = (u16*)(ob + 23330816);         // 4M

  // stage-region scratch (all dead before combine writes stage)
  char* sb = ob + 33554432;
  float* parts = (float*)sb;                     // 24M [gemm3 -> epi]
  u16* pb1     = (u16*)sb;                       // 8M  [gexp1 -> gexp2; after parts dead]
  u16* w1t     = (u16*)(sb + 25165824);          // 4M
  u16* w2te    = (u16*)(sb + 29360128);          // 4M

  char* ws = (char*)d_ws;
  u16* h_hi = (u16*)(ws + WS_HHI);               // 16M
  u16* h_lo = (u16*)(ws + WS_HLO);               // 16M
  u16* pb2  = (u16*)(ws + WS_PB2);               // 32M
  char* ix  = ws + WS_IDX;
  int*   tok    = (int*)(ix + IX_TOK);
  float* gpos   = (float*)(ix + IX_GPOS);
  int*   selE   = (int*)(ix + IX_SELE);
  int*   selP   = (int*)(ix + IX_SELP);
  float* selG   = (float*)(ix + IX_SELG);
  int*   rowsel = (int*)(ix + IX_ROW);
  int*   tileE  = (int*)(ix + IX_TILEE);
  int*   tileL  = (int*)(ix + IX_TILEL);
  int*   tileS  = (int*)(ix + IX_TILES);
  int*   tileC  = (int*)(ix + IX_TILEC);
  int*   meta   = (int*)(ix + IX_META);

  hipMemsetAsync(ix + IX_TILEE, 0, 32768, stream);   // tiles + meta (cnt) = 0

  split_bank_kernel<<<4096, 256, 0, stream>>>(feat_bank, bank_hi, bank_lo);
  wprime_kernel<<<257, 256, 0, stream>>>(fp_w2, r_w1, fp_b2, r_b1, wp, bp);
  prep_main_kernel<<<16896, 256, 0, stream>>>(fp_w1, e_w1, e_w2,
      fpw1t_hi, fpw1t_lo, w1t, w2te);
  prep_rw_kernel<<<1280, 256, 0, stream>>>(r_w1, wp, rw1t_hi, rw1t_lo);
  ln_kernel<<<8192, 256, 0, stream>>>(hidden, ln_g, ln_b, feat, rr_w, rr_b,
                                      h_hi, h_lo, rule);
  // proj1: gelu(bank @ fp_w1 + b1), K=512, split-K=2
  gemm3_kernel<<<dim3(2, 64, 2), 256, 0, stream>>>(
      bank_hi, bank_lo, 512, 256, 2,
      bank_hi, bank_lo, 512, 0, 0,
      fpw1t_hi, fpw1t_lo, 512, parts);
  epi_bf_kernel<<<2048, 256, 0, stream>>>(parts, 2, fp_b1, 1, mid_hi, mid_lo);
  // router (proj2 folded): gelu(h @ r_w1[:1024] + mid @ W' + b'), K=1280
  gemm3_kernel<<<dim3(2, 64, 3), 256, 0, stream>>>(
      h_hi, h_lo, 1024, 512, 2,
      mid_hi, mid_lo, 256, 256, 1024,
      rw1t_hi, rw1t_lo, 1280, parts);
  epi_f32_kernel<<<2048, 256, 0, stream>>>(parts, 3, bp, r1);
  gate_kernel<<<256, 256, 0, stream>>>(r1, r_w2, r_b2, gates, slog, gw,
      tok, gpos, selE, selP, selG, meta);
  tilemap_kernel<<<1, 256, 0, stream>>>(meta, tileE, tileL, tileS, tileC,
      selE, selP, rowsel);
  gexp1_kernel<<<dim3(2, 136), 256, 0, stream>>>(h_hi, w1t, e_b1, tok, gpos,
      tileE, tileL, tileS, tileC, meta, pb1);
  gexp2_kernel<<<dim3(8, 136), 256, 0, stream>>>(pb1, w2te, tileE, tileS, tileC,
      meta, pb2);
  combine_kernel<<<8192, 256, 0, stream>>>(pb2, rowsel, selE, selG, e_b2,
      hidden, alpha, stage, next);
}

// Round 4
// 355.446 us; speedup vs baseline: 1.2048x; 1.2048x over previous
//
#include <hip/hip_runtime.h>
#include <stdint.h>

// ---------------------------------------------------------------------------
// StageBranchRunnerN2 round 4:
//  - gate: NO global atomics (r3's 77us stall: 16384 serialized RMWs on 8
//    addresses). gate -> per-chunk counts; stageB (1 blk) -> bases + tilemap;
//    scatter (256 blk) -> ballot-rank compact rows. All deterministic.
//  - weight transposes via LDS-tiled transpose+split (coalesced both sides).
//  - proj1 split-K=4; e_w2 transpose scheduled after router gemm into dead
//    mid region (ws budget 72 MiB).
// ---------------------------------------------------------------------------

typedef unsigned short u16;
using bf16x8 = __attribute__((ext_vector_type(8))) short;
using f32x4  = __attribute__((ext_vector_type(4))) float;

// ws layout (ws >= 75,497,472 B; we use ~71.6 MB)
#define WS_HHI 0u
#define WS_HLO 16777216u
#define WS_PB2 33554432u
#define WS_W1T 67108864u
#define WS_IDX 71303168u
// idx sub-offsets (bytes from ws+WS_IDX)
#define IX_SELE   0u        // int[16384]
#define IX_SELG   65536u    // float[16384]
#define IX_ROW    131072u   // int[16384]
#define IX_TOKR   196608u   // int[16384]
#define IX_GROW   262144u   // float[16384]
#define IX_CNT    327680u   // int[256*8]
#define IX_CBASE  335872u   // int[256*8]
#define IX_TILEE  344064u   // int[160]
#define IX_TILES  344704u   // int[160]
#define IX_TILEC  345344u   // int[160]
#define IX_META   345984u   // int[32]: [16]=nTiles

__device__ __forceinline__ float gelu_tanh(float x) {
  float x3 = x * x * x;
  float t = tanhf(0.7978845608028654f * (x + 0.044715f * x3));
  return 0.5f * x * (1.0f + t);
}
__device__ __forceinline__ u16 f2bf(float f) {
  uint32_t u = __float_as_uint(f);
  u = u + 0x7fffu + ((u >> 16) & 1u);
  return (u16)(u >> 16);
}
__device__ __forceinline__ float b2f(u16 h) {
  return __uint_as_float(((uint32_t)h) << 16);
}
__device__ __forceinline__ void gll16(const void* g, void* l) {
  __builtin_amdgcn_global_load_lds(
      (const __attribute__((address_space(1))) void*)g,
      (__attribute__((address_space(3))) void*)l, 16, 0, 0);
}

// ---------------------------------------------------------------------------
// split feat_bank (f32) -> hi/lo bf16 (layout already [token][512])
// ---------------------------------------------------------------------------
__global__ __launch_bounds__(256) void split_bank_kernel(const float* __restrict__ x,
    u16* __restrict__ hi, u16* __restrict__ lo) {
  int i4 = blockIdx.x * 256 + threadIdx.x;
  float4 v = ((const float4*)x)[i4];
  ushort4 h, l;
  h.x = f2bf(v.x); l.x = f2bf(v.x - b2f(h.x));
  h.y = f2bf(v.y); l.y = f2bf(v.y - b2f(h.y));
  h.z = f2bf(v.z); l.z = f2bf(v.z - b2f(h.z));
  h.w = f2bf(v.w); l.w = f2bf(v.w - b2f(h.w));
  ((ushort4*)hi)[i4] = h;
  ((ushort4*)lo)[i4] = l;
}

// ---------------------------------------------------------------------------
// LDS-tiled transpose + bf16 split: in f32 [z][inR][inC] -> out bf16
// out[(z*inC + c)*outLD + outColOff + r]. 64x64 tile, coalesced both sides.
// outLo may be null (hi only).
// ---------------------------------------------------------------------------
__global__ __launch_bounds__(256) void tsplit_kernel(const float* __restrict__ in,
    int inR, int inC, u16* __restrict__ outHi, u16* __restrict__ outLo,
    int outLD, int outColOff) {
  __shared__ u16 hs[64][65];
  __shared__ u16 ls[64][65];
  int tid = threadIdx.x;
  int c0 = blockIdx.x * 64, r0 = blockIdx.y * 64;
  const float* inp = in + (size_t)blockIdx.z * inR * inC;
  int rl = tid >> 6, cl = tid & 63;
#pragma unroll
  for (int p = 0; p < 16; p++) {
    int r = rl + p * 4;
    float v = inp[(size_t)(r0 + r) * inC + c0 + cl];
    u16 h = f2bf(v);
    hs[r][cl] = h;
    ls[r][cl] = f2bf(v - b2f(h));
  }
  __syncthreads();
  size_t obase = (size_t)(blockIdx.z * inC + c0) * outLD + outColOff + r0;
#pragma unroll
  for (int p = 0; p < 16; p++) {
    int c = rl + p * 4;
    outHi[obase + (size_t)c * outLD + cl] = hs[cl][c];
    if (outLo) outLo[obase + (size_t)c * outLD + cl] = ls[cl][c];
  }
}

// ---------------------------------------------------------------------------
// W' = fp_w2 @ r_w1[1024:1280,:], b' = r_b1 + fp_b2 @ r_w1[1024:]
// ---------------------------------------------------------------------------
__global__ __launch_bounds__(256) void wprime_kernel(const float* __restrict__ fp_w2,
    const float* __restrict__ r_w1, const float* __restrict__ fp_b2,
    const float* __restrict__ r_b1, float* __restrict__ wp, float* __restrict__ bp) {
  __shared__ float row[256];
  int i = blockIdx.x, n = threadIdx.x;
  if (i < 256) {
    row[n] = fp_w2[i * 256 + n];
    __syncthreads();
    float acc = 0.0f;
    for (int j = 0; j < 256; j++) acc += row[j] * r_w1[(size_t)(1024 + j) * 256 + n];
    wp[i * 256 + n] = acc;
  } else {
    row[n] = fp_b2[n];
    __syncthreads();
    float acc = r_b1[n];
    for (int j = 0; j < 256; j++) acc += row[j] * r_w1[(size_t)(1024 + j) * 256 + n];
    bp[n] = acc;
  }
}

// ---------------------------------------------------------------------------
// LayerNorm -> h hi/lo bf16 split; rule logits.
// ---------------------------------------------------------------------------
__global__ __launch_bounds__(256) void ln_kernel(const float* __restrict__ hidden,
    const float* __restrict__ ln_g, const float* __restrict__ ln_b,
    const float* __restrict__ feat, const float* __restrict__ rr_w,
    const float* __restrict__ rr_b,
    u16* __restrict__ h_hi, u16* __restrict__ h_lo, float* __restrict__ rule) {
  int t = blockIdx.x;
  int tid = threadIdx.x;
  float4 v = ((const float4*)(hidden + (size_t)t * 1024))[tid];
  float s = v.x + v.y + v.z + v.w;
#pragma unroll
  for (int o = 32; o > 0; o >>= 1) s += __shfl_down(s, o);
  __shared__ float red[4];
  __shared__ float stats[2];
  int wid = tid >> 6, lane = tid & 63;
  if (lane == 0) red[wid] = s;
  __syncthreads();
  if (tid == 0) stats[0] = (red[0] + red[1] + red[2] + red[3]) * (1.0f / 1024.0f);
  __syncthreads();
  float mu = stats[0];
  float dx = v.x - mu, dy = v.y - mu, dz = v.z - mu, dw = v.w - mu;
  float q = dx * dx + dy * dy + dz * dz + dw * dw;
#pragma unroll
  for (int o = 32; o > 0; o >>= 1) q += __shfl_down(q, o);
  if (lane == 0) red[wid] = q;
  __syncthreads();
  if (tid == 0) {
    float var = (red[0] + red[1] + red[2] + red[3]) * (1.0f / 1024.0f) + 1e-5f;
    float r = rsqrtf(var);
    r = r * (1.5f - 0.5f * var * r * r);
    stats[1] = r;
  }
  __syncthreads();
  float r = stats[1];
  float4 g = ((const float4*)ln_g)[tid];
  float4 b = ((const float4*)ln_b)[tid];
  float4 o;
  o.x = dx * r * g.x + b.x;
  o.y = dy * r * g.y + b.y;
  o.z = dz * r * g.z + b.z;
  o.w = dw * r * g.w + b.w;
  ushort4 hv, lv;
  hv.x = f2bf(o.x); lv.x = f2bf(o.x - b2f(hv.x));
  hv.y = f2bf(o.y); lv.y = f2bf(o.y - b2f(hv.y));
  hv.z = f2bf(o.z); lv.z = f2bf(o.z - b2f(hv.z));
  hv.w = f2bf(o.w); lv.w = f2bf(o.w - b2f(hv.w));
  ((ushort4*)(h_hi + (size_t)t * 1024))[tid] = hv;
  ((ushort4*)(h_lo + (size_t)t * 1024))[tid] = lv;
  if (tid < 8) {
    float acc = rr_b[tid];
#pragma unroll
    for (int f = 0; f < 16; f++) acc += feat[t * 16 + f] * rr_w[f * 8 + tid];
    rule[t * 8 + tid] = acc;
  }
}

// ---------------------------------------------------------------------------
// split-bf16 3-product MFMA GEMM with split-K (unchanged from r2).
// ---------------------------------------------------------------------------
__global__ __launch_bounds__(256) void gemm3_kernel(
    const u16* __restrict__ Ah, const u16* __restrict__ Al, int lda,
    int kchunk, int nz1,
    const u16* __restrict__ A2h, const u16* __restrict__ A2l, int lda2,
    int klen2, int bkoff2,
    const u16* __restrict__ Bth, const u16* __restrict__ Btl, int Kb,
    float* __restrict__ parts) {
  __shared__ u16 Ash[128 * 32];
  __shared__ u16 Asl[128 * 32];
  __shared__ u16 Bsh[128 * 32];
  __shared__ u16 Bsl[128 * 32];
  int tid = threadIdx.x;
  int z = blockIdx.z;
  const u16 *pAh, *pAl;
  int lda_, akoff, bkoff, klen;
  if (z < nz1) {
    pAh = Ah; pAl = Al; lda_ = lda; akoff = z * kchunk; bkoff = akoff; klen = kchunk;
  } else {
    pAh = A2h; pAl = A2l; lda_ = lda2; akoff = 0; bkoff = bkoff2; klen = klen2;
  }
  int row0 = blockIdx.y * 128, col0 = blockIdx.x * 128;
  int wave = tid >> 6, lane = tid & 63;
  int wr = (wave >> 1) * 64, wc = (wave & 1) * 64;
  int l16 = lane & 15, qd = lane >> 4;
  f32x4 acc[4][4];
#pragma unroll
  for (int i = 0; i < 4; i++)
#pragma unroll
    for (int j = 0; j < 4; j++) acc[i][j] = 0.0f;

  int r0 = tid >> 2, kc = tid & 3;
  const u16* gAh0 = pAh + (size_t)(row0 + r0) * lda_ + akoff + kc * 8;
  const u16* gAh1 = gAh0 + (size_t)64 * lda_;
  const u16* gAl0 = pAl + (size_t)(row0 + r0) * lda_ + akoff + kc * 8;
  const u16* gAl1 = gAl0 + (size_t)64 * lda_;
  const u16* gBh0 = Bth + (size_t)(col0 + r0) * Kb + bkoff + kc * 8;
  const u16* gBh1 = gBh0 + (size_t)64 * Kb;
  const u16* gBl0 = Btl + (size_t)(col0 + r0) * Kb + bkoff + kc * 8;
  const u16* gBl1 = gBl0 + (size_t)64 * Kb;
  u16* dAh = Ash + tid * 8;
  u16* dAl = Asl + tid * 8;
  u16* dBh = Bsh + tid * 8;
  u16* dBl = Bsl + tid * 8;

  for (int k0 = 0; k0 < klen; k0 += 32) {
    __syncthreads();
    gll16(gAh0 + k0, dAh);
    gll16(gAh1 + k0, dAh + 2048);
    gll16(gAl0 + k0, dAl);
    gll16(gAl1 + k0, dAl + 2048);
    gll16(gBh0 + k0, dBh);
    gll16(gBh1 + k0, dBh + 2048);
    gll16(gBl0 + k0, dBl);
    gll16(gBl1 + k0, dBl + 2048);
    __syncthreads();
    bf16x8 afh[4], afl[4], bfh[4], bfl[4];
#pragma unroll
    for (int i = 0; i < 4; i++) {
      afh[i] = *((const bf16x8*)(Ash + (wr + i * 16 + l16) * 32 + qd * 8));
      afl[i] = *((const bf16x8*)(Asl + (wr + i * 16 + l16) * 32 + qd * 8));
      bfh[i] = *((const bf16x8*)(Bsh + (wc + i * 16 + l16) * 32 + qd * 8));
      bfl[i] = *((const bf16x8*)(Bsl + (wc + i * 16 + l16) * 32 + qd * 8));
    }
#pragma unroll
    for (int i = 0; i < 4; i++)
#pragma unroll
      for (int j = 0; j < 4; j++) {
        acc[i][j] = __builtin_amdgcn_mfma_f32_16x16x32_bf16(afh[i], bfh[j], acc[i][j], 0, 0, 0);
        acc[i][j] = __builtin_amdgcn_mfma_f32_16x16x32_bf16(afl[i], bfh[j], acc[i][j], 0, 0, 0);
        acc[i][j] = __builtin_amdgcn_mfma_f32_16x16x32_bf16(afh[i], bfl[j], acc[i][j], 0, 0, 0);
      }
  }

  float* pz = parts + (size_t)z * 2097152;
#pragma unroll
  for (int i = 0; i < 4; i++)
#pragma unroll
    for (int j = 0; j < 4; j++) {
      int cl = wc + j * 16 + l16;
#pragma unroll
      for (int rr = 0; rr < 4; rr++) {
        int rl = wr + i * 16 + qd * 4 + rr;
        pz[(size_t)(row0 + rl) * 256 + col0 + cl] = acc[i][j][rr];
      }
    }
}

// ---------------------------------------------------------------------------
__global__ __launch_bounds__(256) void epi_bf_kernel(const float* __restrict__ parts,
    int nz, const float* __restrict__ bias, int do_gelu,
    u16* __restrict__ hi, u16* __restrict__ lo) {
  int i4 = blockIdx.x * 256 + threadIdx.x;
  float4 s = ((const float4*)parts)[i4];
  for (int zz = 1; zz < nz; zz++) {
    float4 p = ((const float4*)parts)[(size_t)zz * 524288 + i4];
    s.x += p.x; s.y += p.y; s.z += p.z; s.w += p.w;
  }
  float4 bv = ((const float4*)bias)[i4 & 63];
  s.x += bv.x; s.y += bv.y; s.z += bv.z; s.w += bv.w;
  if (do_gelu) {
    s.x = gelu_tanh(s.x); s.y = gelu_tanh(s.y);
    s.z = gelu_tanh(s.z); s.w = gelu_tanh(s.w);
  }
  ushort4 h, l;
  h.x = f2bf(s.x); l.x = f2bf(s.x - b2f(h.x));
  h.y = f2bf(s.y); l.y = f2bf(s.y - b2f(h.y));
  h.z = f2bf(s.z); l.z = f2bf(s.z - b2f(h.z));
  h.w = f2bf(s.w); l.w = f2bf(s.w - b2f(h.w));
  ((ushort4*)hi)[i4] = h;
  ((ushort4*)lo)[i4] = l;
}

__global__ __launch_bounds__(256) void epi_f32_kernel(const float* __restrict__ parts,
    int nz, const float* __restrict__ bias, float* __restrict__ out) {
  int i4 = blockIdx.x * 256 + threadIdx.x;
  float4 s = ((const float4*)parts)[i4];
  for (int zz = 1; zz < nz; zz++) {
    float4 p = ((const float4*)parts)[(size_t)zz * 524288 + i4];
    s.x += p.x; s.y += p.y; s.z += p.z; s.w += p.w;
  }
  float4 bv = ((const float4*)bias)[i4 & 63];
  s.x = gelu_tanh(s.x + bv.x);
  s.y = gelu_tanh(s.y + bv.y);
  s.z = gelu_tanh(s.z + bv.z);
  s.w = gelu_tanh(s.w + bv.w);
  ((float4*)out)[i4] = s;
}

// ---------------------------------------------------------------------------
// Gate: logits, top-2 softmax, outputs, selE/selG, per-chunk counts.
// NO atomics. 32 tokens per block (= one chunk), 256 blocks.
// ---------------------------------------------------------------------------
__global__ __launch_bounds__(256) void gate_kernel(const float* __restrict__ r1,
    const float* __restrict__ r_w2, const float* __restrict__ r_b2,
    float* __restrict__ gates, float* __restrict__ slog, float* __restrict__ gw,
    int* __restrict__ selE, float* __restrict__ selG, int* __restrict__ cnt) {
  __shared__ float w2s[2048];        // [e][k] transposed
  __shared__ float r1s[32][260];
  __shared__ float lg[32][8];
  __shared__ int se_s[64];
  int tid = threadIdx.x;
  int blk = blockIdx.x;
  int t0 = blk * 32;
  for (int i = tid; i < 2048; i += 256) {
    int e = i >> 8, k = i & 255;
    w2s[i] = r_w2[k * 8 + e];
  }
  for (int i = tid; i < 8192; i += 256) {
    int tt = i >> 8, k = i & 255;
    r1s[tt][k] = r1[(size_t)(t0 + tt) * 256 + k];
  }
  __syncthreads();
  {
    int tl = tid >> 3, e = tid & 7;
    float acc = r_b2[e];
    const float* wrp = &w2s[e * 256];
    const float* rrp = &r1s[tl][0];
    for (int k = 0; k < 256; k += 4) {
      float4 a = *(const float4*)(rrp + k);
      float4 b = *(const float4*)(wrp + k);
      acc += a.x * b.x + a.y * b.y + a.z * b.z + a.w * b.w;
    }
    lg[tl][e] = acc;
  }
  __syncthreads();
  if (tid < 32) {
    int t = t0 + tid;
    float l[8];
#pragma unroll
    for (int i = 0; i < 8; i++) l[i] = lg[tid][i];
    float m1 = -1e30f, m2 = -1e30f;
    int i1 = 0, i2 = 0;
#pragma unroll
    for (int i = 0; i < 8; i++) {
      float v = l[i];
      if (v > m1) { m2 = m1; i2 = i1; m1 = v; i1 = i; }
      else if (v > m2) { m2 = v; i2 = i; }
    }
    float w[8];
    float se = 0.0f;
#pragma unroll
    for (int i = 0; i < 8; i++) {
      float ex = (l[i] >= m2) ? expf(l[i] - m1) : 0.0f;
      w[i] = ex;
      se += ex;
    }
    float inv = 1.0f / se;
#pragma unroll
    for (int i = 0; i < 8; i++) {
      gates[(size_t)t * 8 + i] = w[i] * inv;
      slog[(size_t)t * 8 + i] = l[i];
    }
#pragma unroll
    for (int gi = 0; gi < 4; gi++)
      gw[(size_t)t * 4 + gi] = (w[2 * gi] + w[2 * gi + 1]) * inv;
    se_s[tid * 2] = i1;
    se_s[tid * 2 + 1] = i2;
    selE[t * 2] = i1;      selG[t * 2] = w[i1] * inv;
    selE[t * 2 + 1] = i2;  selG[t * 2 + 1] = w[i2] * inv;
  }
  __syncthreads();
  if (tid < 8) {
    int c = 0;
#pragma unroll
    for (int s = 0; s < 64; s++) c += (se_s[s] == tid) ? 1 : 0;
    cnt[blk * 8 + tid] = c;
  }
}

// ---------------------------------------------------------------------------
// stageB: expert totals -> bases -> per-chunk bases; tile map.
// ---------------------------------------------------------------------------
__global__ __launch_bounds__(256) void stageb_kernel(const int* __restrict__ cnt,
    int* __restrict__ cbase, int* __restrict__ tileE, int* __restrict__ tileS,
    int* __restrict__ tileC, int* __restrict__ meta) {
  __shared__ int cs[2048];
  __shared__ int tot[8];
  __shared__ int ebase[8];
  int tid = threadIdx.x;
  for (int i = tid; i < 2048; i += 256) cs[i] = cnt[i];
  __syncthreads();
  if (tid < 8) {
    int s = 0;
    for (int c = 0; c < 256; c++) s += cs[c * 8 + tid];
    tot[tid] = s;
  }
  __syncthreads();
  if (tid == 0) {
    int b = 0, nt = 0;
    for (int e = 0; e < 8; e++) {
      ebase[e] = b;
      int c = tot[e];
      for (int off = 0; off < c; off += 128) {
        tileE[nt] = e; tileS[nt] = b + off;
        tileC[nt] = (c - off < 128) ? (c - off) : 128;
        nt++;
      }
      b += c;
    }
    meta[16] = nt;
  }
  __syncthreads();
  if (tid < 8) {
    int run = ebase[tid];
    for (int c = 0; c < 256; c++) {
      cbase[c * 8 + tid] = run;
      run += cs[c * 8 + tid];
    }
  }
}

// ---------------------------------------------------------------------------
// scatter: ballot-rank compact row assignment. One block per 32-token chunk.
// Wave w handles experts w and w+4 over the chunk's 64 pair-slots.
// ---------------------------------------------------------------------------
__global__ __launch_bounds__(256) void scatter_kernel(const int* __restrict__ selE,
    const float* __restrict__ selG, const int* __restrict__ cbase,
    int* __restrict__ rowsel, int* __restrict__ tokrow, float* __restrict__ grow) {
  int chunk = blockIdx.x;
  int wave = threadIdx.x >> 6, lane = threadIdx.x & 63;
  int slot = chunk * 64 + lane;
  int sel = selE[slot];
  float g = selG[slot];
  int tokn = chunk * 32 + (lane >> 1);
  unsigned long long lt = (1ULL << lane) - 1ULL;
#pragma unroll
  for (int ei = 0; ei < 2; ei++) {
    int e = wave + ei * 4;
    unsigned long long m = __ballot(sel == e);
    if (sel == e) {
      int row = cbase[chunk * 8 + e] + __popcll(m & lt);
      rowsel[slot] = row;
      tokrow[row] = tokn;
      grow[row] = g;
    }
  }
}

// ---------------------------------------------------------------------------
// sparse grouped GEMM1: gelu(gather(h_hi) @ w1t_e + b1_e) * g. K=1024.
// ---------------------------------------------------------------------------
__global__ __launch_bounds__(256) void gexp1_kernel(const u16* __restrict__ A,
    const u16* __restrict__ w1t, const float* __restrict__ e_b1,
    const int* __restrict__ tokrow, const float* __restrict__ grow,
    const int* __restrict__ tileE, const int* __restrict__ tileS,
    const int* __restrict__ tileC, const int* __restrict__ meta,
    u16* __restrict__ pb1) {
  int ty = blockIdx.y;
  if (ty >= meta[16]) return;
  int e = tileE[ty], pstart = tileS[ty], pcnt = tileC[ty];
  if (pcnt <= 0) return;
  __shared__ u16 As[128 * 32];
  __shared__ u16 Bs[128 * 32];
  __shared__ float gsl[128];
  int tid = threadIdx.x;
  int col0 = blockIdx.x * 128;
  if (tid < 128) {
    int rr = (tid < pcnt) ? tid : (pcnt - 1);
    gsl[tid] = grow[pstart + rr];
  }
  int wave = tid >> 6, lane = tid & 63;
  int wr = (wave >> 1) * 64, wc = (wave & 1) * 64;
  int l16 = lane & 15, qd = lane >> 4;
  f32x4 acc[4][4];
#pragma unroll
  for (int i = 0; i < 4; i++)
#pragma unroll
    for (int j = 0; j < 4; j++) acc[i][j] = 0.0f;

  int r0 = tid >> 2, kc = tid & 3;
  int ra = (r0 < pcnt) ? r0 : (pcnt - 1);
  int rb = (r0 + 64 < pcnt) ? (r0 + 64) : (pcnt - 1);
  int ta = tokrow[pstart + ra];
  int tb = tokrow[pstart + rb];
  const u16* Ap0 = A + (size_t)ta * 1024 + kc * 8;
  const u16* Ap1 = A + (size_t)tb * 1024 + kc * 8;
  const u16* Bp0 = w1t + (size_t)(e * 256 + col0 + r0) * 1024 + kc * 8;
  const u16* Bp1 = Bp0 + (size_t)64 * 1024;
  u16* dA = As + tid * 8;
  u16* dB = Bs + tid * 8;

  for (int k0 = 0; k0 < 1024; k0 += 32) {
    __syncthreads();
    gll16(Ap0 + k0, dA);
    gll16(Ap1 + k0, dA + 2048);
    gll16(Bp0 + k0, dB);
    gll16(Bp1 + k0, dB + 2048);
    __syncthreads();
    bf16x8 af[4], bfr[4];
#pragma unroll
    for (int i = 0; i < 4; i++) {
      af[i]  = *((const bf16x8*)(As + (wr + i * 16 + l16) * 32 + qd * 8));
      bfr[i] = *((const bf16x8*)(Bs + (wc + i * 16 + l16) * 32 + qd * 8));
    }
#pragma unroll
    for (int i = 0; i < 4; i++)
#pragma unroll
      for (int j = 0; j < 4; j++)
        acc[i][j] = __builtin_amdgcn_mfma_f32_16x16x32_bf16(af[i], bfr[j], acc[i][j], 0, 0, 0);
  }

#pragma unroll
  for (int i = 0; i < 4; i++)
#pragma unroll
    for (int j = 0; j < 4; j++) {
      int cl = wc + j * 16 + l16;
      int col = col0 + cl;
      float bcol = e_b1[e * 256 + col];
#pragma unroll
      for (int rr = 0; rr < 4; rr++) {
        int rl = wr + i * 16 + qd * 4 + rr;
        if (rl < pcnt) {
          float v = gelu_tanh(acc[i][j][rr] + bcol) * gsl[rl];
          pb1[(size_t)(pstart + rl) * 256 + col] = f2bf(v);
        }
      }
    }
}

// ---------------------------------------------------------------------------
// sparse grouped GEMM2: pb1 @ w2te_e. K=256.
// ---------------------------------------------------------------------------
__global__ __launch_bounds__(256) void gexp2_kernel(const u16* __restrict__ pb1,
    const u16* __restrict__ w2te,
    const int* __restrict__ tileE, const int* __restrict__ tileS,
    const int* __restrict__ tileC, const int* __restrict__ meta,
    u16* __restrict__ pb2) {
  int ty = blockIdx.y;
  if (ty >= meta[16]) return;
  int e = tileE[ty], pstart = tileS[ty], pcnt = tileC[ty];
  if (pcnt <= 0) return;
  __shared__ u16 As[128 * 32];
  __shared__ u16 Bs[128 * 32];
  int tid = threadIdx.x;
  int col0 = blockIdx.x * 128;
  int wave = tid >> 6, lane = tid & 63;
  int wr = (wave >> 1) * 64, wc = (wave & 1) * 64;
  int l16 = lane & 15, qd = lane >> 4;
  f32x4 acc[4][4];
#pragma unroll
  for (int i = 0; i < 4; i++)
#pragma unroll
    for (int j = 0; j < 4; j++) acc[i][j] = 0.0f;

  int r0 = tid >> 2, kc = tid & 3;
  int ra = (r0 < pcnt) ? r0 : (pcnt - 1);
  int rb = (r0 + 64 < pcnt) ? (r0 + 64) : (pcnt - 1);
  const u16* Ap0 = pb1 + (size_t)(pstart + ra) * 256 + kc * 8;
  const u16* Ap1 = pb1 + (size_t)(pstart + rb) * 256 + kc * 8;
  const u16* Bp0 = w2te + (size_t)(e * 1024 + col0 + r0) * 256 + kc * 8;
  const u16* Bp1 = Bp0 + (size_t)64 * 256;
  u16* dA = As + tid * 8;
  u16* dB = Bs + tid * 8;

  for (int k0 = 0; k0 < 256; k0 += 32) {
    __syncthreads();
    gll16(Ap0 + k0, dA);
    gll16(Ap1 + k0, dA + 2048);
    gll16(Bp0 + k0, dB);
    gll16(Bp1 + k0, dB + 2048);
    __syncthreads();
    bf16x8 af[4], bfr[4];
#pragma unroll
    for (int i = 0; i < 4; i++) {
      af[i]  = *((const bf16x8*)(As + (wr + i * 16 + l16) * 32 + qd * 8));
      bfr[i] = *((const bf16x8*)(Bs + (wc + i * 16 + l16) * 32 + qd * 8));
    }
#pragma unroll
    for (int i = 0; i < 4; i++)
#pragma unroll
      for (int j = 0; j < 4; j++)
        acc[i][j] = __builtin_amdgcn_mfma_f32_16x16x32_bf16(af[i], bfr[j], acc[i][j], 0, 0, 0);
  }

#pragma unroll
  for (int i = 0; i < 4; i++)
#pragma unroll
    for (int j = 0; j < 4; j++) {
      int cl = wc + j * 16 + l16;
#pragma unroll
      for (int rr = 0; rr < 4; rr++) {
        int rl = wr + i * 16 + qd * 4 + rr;
        if (rl < pcnt)
          pb2[(size_t)(pstart + rl) * 1024 + col0 + cl] = f2bf(acc[i][j][rr]);
      }
    }
}

// ---------------------------------------------------------------------------
// combine: stage = pairA + pairB + gA*b2[eA] + gB*b2[eB]; next = hidden+a*st.
// ---------------------------------------------------------------------------
__global__ __launch_bounds__(256) void combine_kernel(const u16* __restrict__ pb2,
    const int* __restrict__ rowsel, const int* __restrict__ selE,
    const float* __restrict__ selG, const float* __restrict__ e_b2,
    const float* __restrict__ hidden, const float* __restrict__ alpha_p,
    float* __restrict__ stage, float* __restrict__ next) {
  int t = blockIdx.x;
  int c = threadIdx.x * 4;
  int rA = rowsel[t * 2], rB = rowsel[t * 2 + 1];
  int eA = selE[t * 2], eB = selE[t * 2 + 1];
  float gA = selG[t * 2], gB = selG[t * 2 + 1];
  float al = alpha_p[0];
  ushort4 pa = *((const ushort4*)(pb2 + (size_t)rA * 1024 + c));
  ushort4 pb = *((const ushort4*)(pb2 + (size_t)rB * 1024 + c));
  float4 ba = *((const float4*)(e_b2 + (size_t)eA * 1024 + c));
  float4 bb = *((const float4*)(e_b2 + (size_t)eB * 1024 + c));
  float4 h = *((const float4*)(hidden + (size_t)t * 1024 + c));
  float4 v;
  v.x = b2f(pa.x) + b2f(pb.x) + gA * ba.x + gB * bb.x;
  v.y = b2f(pa.y) + b2f(pb.y) + gA * ba.y + gB * bb.y;
  v.z = b2f(pa.z) + b2f(pb.z) + gA * ba.z + gB * bb.z;
  v.w = b2f(pa.w) + b2f(pb.w) + gA * ba.w + gB * bb.w;
  *((float4*)(stage + (size_t)t * 1024 + c)) = v;
  float4 n;
  n.x = h.x + al * v.x; n.y = h.y + al * v.y;
  n.z = h.z + al * v.z; n.w = h.w + al * v.w;
  *((float4*)(next + (size_t)t * 1024 + c)) = n;
}

// ---------------------------------------------------------------------------
extern "C" void kernel_launch(void* const* d_in, const int* in_sizes, int n_in,
                              void* d_out, int out_size, void* d_ws, size_t ws_size,
                              hipStream_t stream) {
  const float* hidden    = (const float*)d_in[0];
  const float* feat      = (const float*)d_in[1];
  const float* feat_bank = (const float*)d_in[2];
  const float* ln_g  = (const float*)d_in[4];
  const float* ln_b  = (const float*)d_in[5];
  const float* fp_w1 = (const float*)d_in[6];
  const float* fp_b1 = (const float*)d_in[7];
  const float* fp_w2 = (const float*)d_in[8];
  const float* fp_b2 = (const float*)d_in[9];
  const float* r_w1  = (const float*)d_in[10];
  const float* r_b1  = (const float*)d_in[11];
  const float* r_w2  = (const float*)d_in[12];
  const float* r_b2  = (const float*)d_in[13];
  const float* rr_w  = (const float*)d_in[14];
  const float* rr_b  = (const float*)d_in[15];
  const float* e_w1  = (const float*)d_in[16];
  const float* e_b1  = (const float*)d_in[17];
  const float* e_w2  = (const float*)d_in[18];
  const float* e_b2  = (const float*)d_in[19];
  const float* alpha = (const float*)d_in[20];

  char* ob = (char*)d_out;
  float* next  = (float*)ob;
  float* stage = (float*)(ob + 33554432);
  float* gates = (float*)(ob + 67108864);
  float* slog  = gates + 65536;
  float* gw    = slog + 65536;
  float* rule  = gw + 32768;

  // next-region scratch (all dead before combine writes next)
  u16* bank_hi  = (u16*)ob;                      // 8M   [-> proj1]
  u16* bank_lo  = (u16*)(ob + 8388608);          // 8M
  float* r1     = (float*)ob;                    // 8M   [epi_f32 -> gate; after bank dead]
  u16* fpw1t_hi = (u16*)(ob + 16777216);         // 256K [-> proj1]
  u16* fpw1t_lo = (u16*)(ob + 17039360);         // 256K
  float* wp     = (float*)(ob + 17301504);       // 256K [wprime -> tsplit]
  float* bp     = (float*)(ob + 17563648);       // 1K   [-> epi_f32]
  u16* rw1t_hi  = (u16*)(ob + 17825792);         // 640K [-> router]
  u16* rw1t_lo  = (u16*)(ob + 18481152);         // 640K
  u16* mid_hi   = (u16*)(ob + 19136512);         // 4M   [epi1 -> router]
  u16* mid_lo   = (u16*)(ob + 23330816);         // 4M
  u16* w2te     = (u16*)(ob + 19136512);         // 4M   [written AFTER router]

  // stage-region scratch (all dead before combine writes stage)
  char* sb = ob + 33554432;
  float* parts = (float*)sb;                     // up to 32M [gemm3 -> epi]
  u16* pb1     = (u16*)sb;                       // 8M  [gexp1 -> gexp2; after parts dead]

  char* ws = (char*)d_ws;
  u16* h_hi = (u16*)(ws + WS_HHI);               // 16M
  u16* h_lo = (u16*)(ws + WS_HLO);               // 16M
  u16* pb2  = (u16*)(ws + WS_PB2);               // 32M
  u16* w1t  = (u16*)(ws + WS_W1T);               // 4M
  char* ix  = ws + WS_IDX;
  int*   selE   = (int*)(ix + IX_SELE);
  float* selG   = (float*)(ix + IX_SELG);
  int*   rowsel = (int*)(ix + IX_ROW);
  int*   tokrow = (int*)(ix + IX_TOKR);
  float* grow   = (float*)(ix + IX_GROW);
  int*   cnt    = (int*)(ix + IX_CNT);
  int*   cbase  = (int*)(ix + IX_CBASE);
  int*   tileE  = (int*)(ix + IX_TILEE);
  int*   tileS  = (int*)(ix + IX_TILES);
  int*   tileC  = (int*)(ix + IX_TILEC);
  int*   meta   = (int*)(ix + IX_META);

  split_bank_kernel<<<4096, 256, 0, stream>>>(feat_bank, bank_hi, bank_lo);
  wprime_kernel<<<257, 256, 0, stream>>>(fp_w2, r_w1, fp_b2, r_b1, wp, bp);
  // transposed/split weights (coalesced LDS-tiled)
  tsplit_kernel<<<dim3(4, 8, 1), 256, 0, stream>>>(fp_w1, 512, 256,
      fpw1t_hi, fpw1t_lo, 512, 0);
  tsplit_kernel<<<dim3(4, 16, 1), 256, 0, stream>>>(r_w1, 1024, 256,
      rw1t_hi, rw1t_lo, 1280, 0);
  tsplit_kernel<<<dim3(4, 4, 1), 256, 0, stream>>>(wp, 256, 256,
      rw1t_hi, rw1t_lo, 1280, 1024);
  tsplit_kernel<<<dim3(4, 16, 8), 256, 0, stream>>>(e_w1, 1024, 256,
      w1t, nullptr, 1024, 0);
  ln_kernel<<<8192, 256, 0, stream>>>(hidden, ln_g, ln_b, feat, rr_w, rr_b,
                                      h_hi, h_lo, rule);
  // proj1: gelu(bank @ fp_w1 + b1), K=512, split-K=4
  gemm3_kernel<<<dim3(2, 64, 4), 256, 0, stream>>>(
      bank_hi, bank_lo, 512, 128, 4,
      bank_hi, bank_lo, 512, 0, 0,
      fpw1t_hi, fpw1t_lo, 512, parts);
  epi_bf_kernel<<<2048, 256, 0, stream>>>(parts, 4, fp_b1, 1, mid_hi, mid_lo);
  // router (proj2 folded): gelu(h @ r_w1[:1024] + mid @ W' + b'), K=1280
  gemm3_kernel<<<dim3(2, 64, 3), 256, 0, stream>>>(
      h_hi, h_lo, 1024, 512, 2,
      mid_hi, mid_lo, 256, 256, 1024,
      rw1t_hi, rw1t_lo, 1280, parts);
  // e_w2 transpose into the now-dead mid region (after router gemm)
  tsplit_kernel<<<dim3(16, 4, 8), 256, 0, stream>>>(e_w2, 256, 1024,
      w2te, nullptr, 256, 0);
  epi_f32_kernel<<<2048, 256, 0, stream>>>(parts, 3, bp, r1);
  gate_kernel<<<256, 256, 0, stream>>>(r1, r_w2, r_b2, gates, slog, gw,
      selE, selG, cnt);
  stageb_kernel<<<1, 256, 0, stream>>>(cnt, cbase, tileE, tileS, tileC, meta);
  scatter_kernel<<<256, 256, 0, stream>>>(selE, selG, cbase, rowsel, tokrow, grow);
  gexp1_kernel<<<dim3(2, 136), 256, 0, stream>>>(h_hi, w1t, e_b1, tokrow, grow,
      tileE, tileS, tileC, meta, pb1);
  gexp2_kernel<<<dim3(8, 136), 256, 0, stream>>>(pb1, w2te, tileE, tileS, tileC,
      meta, pb2);
  combine_kernel<<<8192, 256, 0, stream>>>(pb2, rowsel, selE, selG, e_b2,
      hidden, alpha, stage, next);
}